// Round 8
// baseline (224.371 us; speedup 1.0000x reference)
//
#include <hip/hip_runtime.h>

#define KK 8
#define DD 16
#define NN 32
#define TT 200
#define BB 2048
#define HLP 0.91893853320467274178f   // 0.5*log(2*pi)

// row pointer is WAVE-UNIFORM in all call sites -> uniformity analysis
// emits s_load + scalar-operand v_fma (1 SGPR src per VALU inst: legal)
__device__ __forceinline__ float dot16(const float* __restrict__ row,
                                       const float* __restrict__ z) {
  const float4* r4 = reinterpret_cast<const float4*>(row);
  float4 c0 = r4[0], c1 = r4[1], c2 = r4[2], c3 = r4[3];
  float a = c0.x * z[0], b = c0.y * z[1];
  a = fmaf(c0.z, z[2], a);  b = fmaf(c0.w, z[3], b);
  a = fmaf(c1.x, z[4], a);  b = fmaf(c1.y, z[5], b);
  a = fmaf(c1.z, z[6], a);  b = fmaf(c1.w, z[7], b);
  a = fmaf(c2.x, z[8], a);  b = fmaf(c2.y, z[9], b);
  a = fmaf(c2.z, z[10], a); b = fmaf(c2.w, z[11], b);
  a = fmaf(c3.x, z[12], a); b = fmaf(c3.y, z[13], b);
  a = fmaf(c3.z, z[14], a); b = fmaf(c3.w, z[15], b);
  return a + b;
}

__device__ __forceinline__ void load16lds(float* __restrict__ d,
                                          const float* __restrict__ s) {
  const float4* p = reinterpret_cast<const float4*>(s);
  float4 a0 = p[0], a1 = p[1], a2 = p[2], a3 = p[3];
  d[0] = a0.x;  d[1] = a0.y;  d[2] = a0.z;  d[3] = a0.w;
  d[4] = a1.x;  d[5] = a1.y;  d[6] = a1.z;  d[7] = a1.w;
  d[8] = a2.x;  d[9] = a2.y;  d[10] = a2.z; d[11] = a2.w;
  d[12] = a3.x; d[13] = a3.y; d[14] = a3.z; d[15] = a3.w;
}

// THEORY (R8): R2/R3/R5 all pin at 42-45us across 16->32 waves/CU -> the
// LDS RETURN PATH is saturated: 220 ds_read_b128/item x 1KB-to-RF each
// (~12cyc, m134) ~= 27us floor. Fix: block-local counting sort of 256-item
// chunks by k, process sorted slots in <=~2.7 wave-uniform k-passes; table
// operands become s_load SCALARS (no per-lane copies AT ALL). Item data
// (z/obs) staged COALESCED into LDS once, gathered divergently (the cheap
// m134 case, ~60 b128/item total). Cost shifts to VALU (~2.7x issue
// duplication via discarded lanes) -> VALU-bound ~20us target.
// R6 lesson honored: no global scatter -- all gathers are LDS-window-local.
// Per-item math is R5's EXACT fold order -> bit-identical lp; reduction is
// R5's proven natural-order segmented shuffle-sum (from LDS, full waves).
// LDS 52.7KB -> 3 blocks/CU; 800 blocks/768 slots = 1.04 rounds.
__global__ __launch_bounds__(256) void slds_lp_kernel(
    const int* __restrict__ dsts,      // [B,T]
    const float* __restrict__ zg,      // [B,T,D]
    const float* __restrict__ obsg,    // [B,T,N]
    const float* __restrict__ initlg,  // [K]
    const float* __restrict__ initloc, // [K,D]
    const float* __restrict__ initls,  // [K,D]
    const float* __restrict__ transg,  // [K,K]
    const float* __restrict__ Ag,      // [K,D,D]
    const float* __restrict__ dynoff,  // [K,D]
    const float* __restrict__ dynls,   // [K,D] (scale directly, NOT log)
    const float* __restrict__ Cg,      // [K,N,D]
    const float* __restrict__ emoff,   // [K,N]
    const float* __restrict__ emls,    // [K,N]
    float* __restrict__ out)           // [B]
{
  __shared__ __align__(16) float zS[257 * DD];   // 16448 B: z[cbase-1 .. cbase+255]
  __shared__ __align__(16) float oS[256 * NN];   // 32768 B
  __shared__ float lpS[512];                     // 2048 B (natural order)
  __shared__ int   sidx[256];                    // 1024 B: (iofs<<3)|k
  __shared__ float sTrans[KK * KK];              // 256 B
  __shared__ int   cnt[KK];
  const int tid = threadIdx.x;

  if (tid < KK * KK) {                 // transition log-softmax (as R5)
    int kr = tid >> 3;
    float mx = transg[kr * KK];
    for (int j = 1; j < KK; ++j) mx = fmaxf(mx, transg[kr * KK + j]);
    float ss = 0.f;
    for (int j = 0; j < KK; ++j) ss += expf(transg[kr * KK + j] - mx);
    sTrans[tid] = transg[tid] - (logf(ss) + mx);
  }

  for (int c = 0; c < 2; ++c) {
    const int cbase = blockIdx.x * 512 + c * 256;
    if (tid < KK) cnt[tid] = 0;
    __syncthreads();                   // prev chunk done; cnt zeroed

    // ---- stage z window [cbase-1, cbase+256) and obs (coalesced) ----
    {
      float4* zS4 = reinterpret_cast<float4*>(zS);
      const long zofs4 = (long)(cbase - 1) * (DD / 4);   // float4 units
      for (int i = tid; i < 257 * (DD / 4); i += 256) {
        long src = zofs4 + i;
        zS4[i] = reinterpret_cast<const float4*>(zg)[src < 0 ? 0 : src];
      }
      float4* oS4 = reinterpret_cast<float4*>(oS);
      const size_t oofs4 = (size_t)cbase * (NN / 4);
      for (int i = tid; i < 256 * (NN / 4); i += 256)
        oS4[i] = reinterpret_cast<const float4*>(obsg)[oofs4 + i];
    }
    const int myk = dsts[cbase + tid];           // coalesced
    atomicAdd(&cnt[myk], 1);
    __syncthreads();
    if (tid == 0) {                              // exclusive prefix -> cursors
      int run = 0;
      for (int k = 0; k < KK; ++k) { int v = cnt[k]; cnt[k] = run; run += v; }
    }
    __syncthreads();
    {
      int pos = atomicAdd(&cnt[myk], 1);         // intra-bucket order free
      sidx[pos] = (tid << 3) | myk;
    }
    __syncthreads();

    // ---- compute: thread owns sorted slot tid ----
    const int pk   = sidx[tid];
    const int iofs = pk >> 3;
    const int sk   = pk & 7;
    const int item = cbase + iofs;
    const int t    = item - (item / TT) * TT;
    const int sp   = dsts[item - (t != 0 ? 1 : 0)];  // gather, L1-hot

    float z[16], zp[16];
    load16lds(z,  &zS[(iofs + 1) * DD]);
    load16lds(zp, &zS[iofs * DD]);               // garbage for t==0, discarded

    float lp = 0.f;
    for (int k = 0; k < KK; ++k) {               // uniform loop
      if (!__any(sk == k)) continue;             // uniform wave-skip
      // ---- UNIFORM region: all table reads scalarize ----
      const float* __restrict__ Ak  = Ag     + k * (DD * DD);
      const float* __restrict__ dof = dynoff + k * DD;
      const float* __restrict__ dls = dynls  + k * DD;
      const float* __restrict__ Ck  = Cg     + k * (NN * DD);
      const float* __restrict__ eof = emoff  + k * NN;
      const float* __restrict__ els = emls   + k * NN;

      // dynamics (computed by all lanes; selected below) -- R5 fold order
      float a2d = 0.f;
#pragma unroll
      for (int g = 0; g < 4; ++g) {
        const int i0 = g * 4;
        float4 off = reinterpret_cast<const float4*>(dof)[g];
        float4 lsv = reinterpret_cast<const float4*>(dls)[g];
        float l0 = dot16(&Ak[(i0 + 0) * DD], zp) + off.x;
        float l1 = dot16(&Ak[(i0 + 1) * DD], zp) + off.y;
        float l2 = dot16(&Ak[(i0 + 2) * DD], zp) + off.z;
        float l3 = dot16(&Ak[(i0 + 3) * DD], zp) + off.w;
        float d0 = (z[i0 + 0] - l0) * (1.0f / lsv.x);
        float d1 = (z[i0 + 1] - l1) * (1.0f / lsv.y);
        float d2 = (z[i0 + 2] - l2) * (1.0f / lsv.z);
        float d3 = (z[i0 + 3] - l3) * (1.0f / lsv.w);
        a2d = fmaf(d0, d0, a2d); a2d = fmaf(d1, d1, a2d);
        a2d = fmaf(d2, d2, a2d); a2d = fmaf(d3, d3, a2d);
      }
      float sd = 0.f;                            // dynConst, R5 serial order
      for (int d = 0; d < DD; ++d) sd -= logf(dls[d]);
      float lpk = -0.5f * a2d + (sd - DD * HLP) + sTrans[sp * KK + k];

      if (t == 0) {                              // rare; R5's global-init path
        const float* __restrict__ ploc = initloc + k * DD;
        const float* __restrict__ pls  = initls + k * DD;
        float a2i = 0.f;
#pragma unroll
        for (int g = 0; g < 4; ++g) {
          const int i0 = g * 4;
          float4 loc = reinterpret_cast<const float4*>(ploc)[g];
          float4 ls  = reinterpret_cast<const float4*>(pls)[g];
          float d0 = (z[i0 + 0] - loc.x) * expf(-ls.x);
          float d1 = (z[i0 + 1] - loc.y) * expf(-ls.y);
          float d2 = (z[i0 + 2] - loc.z) * expf(-ls.z);
          float d3 = (z[i0 + 3] - loc.w) * expf(-ls.w);
          a2i = fmaf(d0, d0, a2i); a2i = fmaf(d1, d1, a2i);
          a2i = fmaf(d2, d2, a2i); a2i = fmaf(d3, d3, a2i);
        }
        float mx = initlg[0];
        for (int j = 1; j < KK; ++j) mx = fmaxf(mx, initlg[j]);
        float ss = 0.f;
        for (int j = 0; j < KK; ++j) ss += expf(initlg[j] - mx);
        float si = 0.f;
        for (int d = 0; d < DD; ++d) si -= initls[k * DD + d];
        lpk = -0.5f * a2i + (initlg[k] - (logf(ss) + mx) + si - DD * HLP);
      }

      // emissions -- R5 fold order; o gathered per group from LDS window
      {
        const float4* o4 = reinterpret_cast<const float4*>(&oS[iofs * NN]);
        float acc = 0.f;
#pragma unroll 2
        for (int g = 0; g < 8; ++g) {
          float4 o   = o4[g];
          float4 off = reinterpret_cast<const float4*>(eof)[g];
          float4 ls  = reinterpret_cast<const float4*>(els)[g];
          float iv0 = expf(-ls.x), iv1 = expf(-ls.y);
          float iv2 = expf(-ls.z), iv3 = expf(-ls.w);
          int n0 = g * 4;
          float l0 = dot16(&Ck[(n0 + 0) * DD], z) + off.x;
          float l1 = dot16(&Ck[(n0 + 1) * DD], z) + off.y;
          float l2 = dot16(&Ck[(n0 + 2) * DD], z) + off.z;
          float l3 = dot16(&Ck[(n0 + 3) * DD], z) + off.w;
          float d0 = (o.x - l0) * iv0;
          float d1 = (o.y - l1) * iv1;
          float d2 = (o.z - l2) * iv2;
          float d3 = (o.w - l3) * iv3;
          acc = fmaf(d0, d0, acc); acc = fmaf(d1, d1, acc);
          acc = fmaf(d2, d2, acc); acc = fmaf(d3, d3, acc);
        }
        float se = 0.f;                          // emConst, R5 serial order
        for (int n = 0; n < NN; ++n) se -= els[n];
        lpk += -0.5f * acc + (se - NN * HLP);
      }

      if (sk == k) lp = lpk;                     // select own pass
    }

    lpS[c * 256 + iofs] = lp;                    // restore natural order
    __syncthreads();                             // chunk done
  }

  // ---- R5's segmented shuffle-sum, natural order, full waves only ----
  const int lane = tid & 63;
  for (int p = 0; p < 2; ++p) {
    const int ofs = p * 256 + tid;
    const int item = blockIdx.x * 512 + ofs;
    const int b = item / TT;
    float v = lpS[ofs];
#pragma unroll
    for (int off = 1; off < 64; off <<= 1) {
      float ov = __shfl_up(v, off, 64);
      int obk = __shfl_up(b, off, 64);
      if (lane >= off && obk == b) v += ov;
    }
    int nb = __shfl_down(b, 1, 64);
    if (lane == 63 || nb != b) atomicAdd(&out[b], v);
  }
}

extern "C" void kernel_launch(void* const* d_in, const int* in_sizes, int n_in,
                              void* d_out, int out_size, void* d_ws, size_t ws_size,
                              hipStream_t stream) {
  const int*   dsts    = (const int*)d_in[0];
  const float* zg      = (const float*)d_in[1];
  const float* obsg    = (const float*)d_in[2];
  const float* initlg  = (const float*)d_in[3];
  const float* initloc = (const float*)d_in[4];
  const float* initls  = (const float*)d_in[5];
  const float* transg  = (const float*)d_in[6];
  const float* Ag      = (const float*)d_in[7];
  const float* dynoff  = (const float*)d_in[8];
  const float* dynls   = (const float*)d_in[9];
  const float* Cg      = (const float*)d_in[10];
  const float* emoff   = (const float*)d_in[11];
  const float* emls    = (const float*)d_in[12];
  float* out = (float*)d_out;

  hipMemsetAsync(d_out, 0, BB * sizeof(float), stream);

  // 800 blocks x 512 items (2 sorted chunks of 256) == exactly B*T
  slds_lp_kernel<<<800, 256, 0, stream>>>(dsts, zg, obsg, initlg, initloc,
                                          initls, transg, Ag, dynoff, dynls,
                                          Cg, emoff, emls, out);
}